// Round 1
// baseline (154.263 us; speedup 1.0000x reference)
//
#include <hip/hip_runtime.h>
#include <hip/hip_bf16.h>

// Problem constants (from reference): IN=4, H=30, OUT=1, N_UNIT=100, B=262144.
// out = [B,100] fp32. Memory floor ~109 MB / 6.3 TB/s ~= 17.3 us -> memory-bound target.
//
// ws layout (floats):
//   [0    .. 959 ]  W2TB: [k*32 + i] = W2[i][k] for i<30; [k*32+30]=b2[k]; [k*32+31]=W3[k]
//   [960  .. 1199]  W1TB: [k*8  + i] = W1[i][k] for i<4;  [k*8+4]=b1[k];  pads 0
//   [1200 .. 1299]  cumprev[j] = sum of Pmax[i] over units strictly cheaper than j
//                   (stable tie-break on index == jnp stable argsort exclusive cumsum)
//   [1300]          sum(Pd)

#define B_ROWS 262144
#define ROWS_PER_BLOCK 512
#define NBLOCKS (B_ROWS / ROWS_PER_BLOCK)

__global__ __launch_bounds__(128) void prep_kernel(
    const float* __restrict__ Cost, const float* __restrict__ Pmax,
    const float* __restrict__ Pd,   const float* __restrict__ W1,
    const float* __restrict__ b1,   const float* __restrict__ W2,
    const float* __restrict__ b2,   const float* __restrict__ W3,
    float* __restrict__ ws) {
  const int t = threadIdx.x;

  // W2 transposed + padded (stride 32), b2 and W3 folded into pad slots 30/31
  for (int idx = t; idx < 960; idx += 128) {
    const int k = idx >> 5, i = idx & 31;
    float v;
    if (i < 30)      v = W2[i * 30 + k];
    else if (i == 30) v = b2[k];
    else             v = W3[k];
    ws[idx] = v;
  }
  // W1 transposed + padded (stride 8), b1 folded into slot 4
  for (int idx = t; idx < 240; idx += 128) {
    const int k = idx >> 3, i = idx & 7;
    float v = 0.0f;
    if (i < 4)       v = W1[i * 30 + k];
    else if (i == 4) v = b1[k];
    ws[960 + idx] = v;
  }
  // cumprev via O(N^2) rank-sum (N=100, trivial)
  if (t < 100) {
    const float c = Cost[t];
    float s = 0.0f;
    for (int i = 0; i < 100; ++i) {
      const float ci = Cost[i];
      if (ci < c || (ci == c && i < t)) s += Pmax[i];
    }
    ws[1200 + t] = s;
  }
  if (t == 0) {
    float s = 0.0f;
    for (int i = 0; i < 100; ++i) s += Pd[i];
    ws[1300] = s;
  }
}

__global__ __launch_bounds__(256, 2) void mlp_dispatch_kernel(
    const float* __restrict__ x,     const float* __restrict__ Pmax,
    const float* __restrict__ wcapp, const float* __restrict__ b3p,
    const float* __restrict__ ws,    float* __restrict__ out) {
  // s[0..1199]   : staged weights (same layout as ws[0..1199])
  // s[1200..1711]: total_d for this block's 512 rows
  __shared__ float s[1200 + ROWS_PER_BLOCK];
  const int t = threadIdx.x;
  const long rbase = (long)blockIdx.x * ROWS_PER_BLOCK;

  for (int i = t; i < 1200; i += 256) s[i] = ws[i];
  __syncthreads();

  // ---- Phase 1: MLP for 2 rows per thread (weight broadcasts amortized 2x) ----
  const float4* __restrict__ x4 = (const float4*)x;
  const float4 xa = x4[rbase + t];
  const float4 xb = x4[rbase + 256 + t];

  float h1a[30], h1b[30];
#pragma unroll
  for (int k = 0; k < 30; ++k) {
    const float4 w = *(const float4*)&s[960 + k * 8];
    const float bb = s[960 + k * 8 + 4];
    float pa = fmaf(xa.x, w.x, fmaf(xa.y, w.y, fmaf(xa.z, w.z, fmaf(xa.w, w.w, bb))));
    float pb = fmaf(xb.x, w.x, fmaf(xb.y, w.y, fmaf(xb.z, w.z, fmaf(xb.w, w.w, bb))));
    h1a[k] = fmaxf(pa, 0.0f);
    h1b[k] = fmaxf(pb, 0.0f);
  }

  float ya = 0.0f, yb = 0.0f;
#pragma unroll 2
  for (int k = 0; k < 30; ++k) {
    const float4* __restrict__ wr = (const float4*)&s[k * 32];
    float sa = 0.0f, sb = 0.0f;
#pragma unroll
    for (int c = 0; c < 7; ++c) {
      const float4 w = wr[c];
      sa = fmaf(h1a[4 * c], w.x, sa); sb = fmaf(h1b[4 * c], w.x, sb);
      sa = fmaf(h1a[4 * c + 1], w.y, sa); sb = fmaf(h1b[4 * c + 1], w.y, sb);
      sa = fmaf(h1a[4 * c + 2], w.z, sa); sb = fmaf(h1b[4 * c + 2], w.z, sb);
      sa = fmaf(h1a[4 * c + 3], w.w, sa); sb = fmaf(h1b[4 * c + 3], w.w, sb);
    }
    const float4 w7 = wr[7];  // {W2[28][k], W2[29][k], b2[k], W3[k]}
    sa = fmaf(h1a[28], w7.x, fmaf(h1a[29], w7.y, sa)) + w7.z;
    sb = fmaf(h1b[28], w7.x, fmaf(h1b[29], w7.y, sb)) + w7.z;
    sa = fmaxf(sa, 0.0f);
    sb = fmaxf(sb, 0.0f);
    ya = fmaf(sa, w7.w, ya);
    yb = fmaf(sb, w7.w, yb);
  }

  const float wc  = wcapp[0];
  const float b3v = b3p[0];
  const float spd = ws[1300];
  s[1200 + t]       = spd - wc * (ya + b3v);
  s[1200 + 256 + t] = spd - wc * (yb + b3v);
  __syncthreads();

  // ---- Phase 2: dispatch + coalesced float4 stores ----
  // threads t<200: fixed column group g=t%25 (j0=4g), row phase r=t/25 (0..7),
  // sweep rows in steps of 8. cumprev/Pmax for the fixed columns live in regs.
  if (t < 200) {
    const int g = t % 25;
    int r = t / 25;
    const float4 cpr = *(const float4*)&ws[1200 + g * 4];
    const float4 pmx = *(const float4*)&Pmax[g * 4];
    const float* __restrict__ sld = &s[1200];
    float* __restrict__ op = out + (rbase + r) * 100 + g * 4;
#pragma unroll 4
    for (int it = 0; it < ROWS_PER_BLOCK / 8; ++it) {
      const float td = sld[r];
      float4 v;
      v.x = fminf(fmaxf(td - cpr.x, 0.0f), pmx.x);
      v.y = fminf(fmaxf(td - cpr.y, 0.0f), pmx.y);
      v.z = fminf(fmaxf(td - cpr.z, 0.0f), pmx.z);
      v.w = fminf(fmaxf(td - cpr.w, 0.0f), pmx.w);
      *(float4*)op = v;
      r += 8;
      op += 800;
    }
  }
}

extern "C" void kernel_launch(void* const* d_in, const int* in_sizes, int n_in,
                              void* d_out, int out_size, void* d_ws, size_t ws_size,
                              hipStream_t stream) {
  const float* x    = (const float*)d_in[0];
  const float* Cost = (const float*)d_in[1];
  const float* Pmax = (const float*)d_in[2];
  const float* Pd   = (const float*)d_in[3];
  const float* wcap = (const float*)d_in[4];
  const float* W1   = (const float*)d_in[5];
  const float* b1   = (const float*)d_in[6];
  const float* W2   = (const float*)d_in[7];
  const float* b2   = (const float*)d_in[8];
  const float* W3   = (const float*)d_in[9];
  const float* b3   = (const float*)d_in[10];
  float* out = (float*)d_out;
  float* ws  = (float*)d_ws;  // needs 1301 floats (~5.1 KB)

  prep_kernel<<<1, 128, 0, stream>>>(Cost, Pmax, Pd, W1, b1, W2, b2, W3, ws);
  mlp_dispatch_kernel<<<NBLOCKS, 256, 0, stream>>>(x, Pmax, wcap, b3, ws, out);
}

// Round 2
// 148.674 us; speedup vs baseline: 1.0376x; 1.0376x over previous
//
#include <hip/hip_runtime.h>
#include <hip/hip_bf16.h>

// Fused single-kernel version.
// B=262144 rows, out [B,100] fp32 = 104.9 MB -> ~16.5 us write floor at the
// fill-measured 6.5 TB/s. MLP VALU floor ~7.5 us with packed fp32
// (v_pk_fma_f32: 2 rows per lane in a <2 x float>).
// Structure per block (256 blocks x 256 threads, 1024 rows/block):
//   prep (weights->LDS transpose, cumprev, sum Pd)  [replaces old prep kernel]
//   chain0: packed MLP for rows [0,512)   -> td in LDS
//   barrier
//   store batch0 (posted writes drain in background) ; chain1: rows [512,1024)
//   barrier
//   store batch1
// The batch-0 stores overlap chain-1 compute -> total ~= drain time + startup,
// not compute + drain.

typedef float f2 __attribute__((ext_vector_type(2)));

#define NBLOCKS 256
#define ROWS_PER_BLOCK 1024

// smem layout (floats)
#define OFF_W2 0      // [k*32+i]=W2[i][k] i<30; +30=b2[k]; +31=W3[k]   (960)
#define OFF_W1 960    // [k*8+i]=W1[i][k] i<4; +4=b1[k]; pads 0         (240)
#define OFF_CP 1200   // cumprev[j]                                     (100)
#define OFF_PM 1300   // Pmax staged                                    (100)
#define OFF_CS 1400   // Cost staged                                    (100)
#define OFF_SPD 1500  // sum(Pd)                                        (1)
#define OFF_Y 1504    // td buffer, 1024 rows
#define SMEM_FLOATS (OFF_Y + ROWS_PER_BLOCK)

__device__ __forceinline__ f2 splat(float v) { return (f2){v, v}; }

// Packed MLP for two rows (xa -> .x lane, xb -> .y lane). Returns total_d pair.
__device__ __forceinline__ f2 mlp_pair(const float4 xa, const float4 xb,
                                       const float* __restrict__ s,
                                       float wc, float b3v, float spd) {
  const f2 X0 = {xa.x, xb.x}, X1 = {xa.y, xb.y};
  const f2 X2 = {xa.z, xb.z}, X3 = {xa.w, xb.w};
  const f2 zero = {0.0f, 0.0f};

  f2 h1[30];
#pragma unroll
  for (int k = 0; k < 30; ++k) {
    const float4 w = *(const float4*)&s[OFF_W1 + k * 8];
    const float bb = s[OFF_W1 + k * 8 + 4];
    f2 p = splat(bb);
    p = __builtin_elementwise_fma(X0, splat(w.x), p);
    p = __builtin_elementwise_fma(X1, splat(w.y), p);
    p = __builtin_elementwise_fma(X2, splat(w.z), p);
    p = __builtin_elementwise_fma(X3, splat(w.w), p);
    h1[k] = __builtin_elementwise_max(p, zero);
  }

  f2 y = zero;
#pragma unroll 2
  for (int k = 0; k < 30; ++k) {
    const float4* __restrict__ wr = (const float4*)&s[OFF_W2 + k * 32];
    // two partial accumulators -> two independent FMA chains (latency hiding
    // matters: only 1 wave/SIMD at this grid)
    f2 sa = zero, sb = zero;
#pragma unroll
    for (int c = 0; c < 7; ++c) {
      const float4 w = wr[c];
      sa = __builtin_elementwise_fma(h1[4 * c],     splat(w.x), sa);
      sb = __builtin_elementwise_fma(h1[4 * c + 1], splat(w.y), sb);
      sa = __builtin_elementwise_fma(h1[4 * c + 2], splat(w.z), sa);
      sb = __builtin_elementwise_fma(h1[4 * c + 3], splat(w.w), sb);
    }
    const float4 w7 = wr[7];  // {W2[28][k], W2[29][k], b2[k], W3[k]}
    sa = __builtin_elementwise_fma(h1[28], splat(w7.x), sa);
    sb = __builtin_elementwise_fma(h1[29], splat(w7.y), sb);
    f2 s2 = sa + sb + splat(w7.z);
    s2 = __builtin_elementwise_max(s2, zero);
    y = __builtin_elementwise_fma(s2, splat(w7.w), y);
  }

  f2 td;
  td.x = spd - wc * (y.x + b3v);
  td.y = spd - wc * (y.y + b3v);
  return td;
}

__device__ __forceinline__ void store_batch(float* __restrict__ op0,
                                            const float* __restrict__ ytd,
                                            const float4 cpr, const float4 pmx,
                                            int t) {
  if (t < 200) {
    const int g = t % 25;
    int r = t / 25;
    float* __restrict__ op = op0 + r * 100 + g * 4;
#pragma unroll 4
    for (int it = 0; it < 64; ++it) {
      const float td = ytd[r];
      float4 v;
      v.x = fminf(fmaxf(td - cpr.x, 0.0f), pmx.x);
      v.y = fminf(fmaxf(td - cpr.y, 0.0f), pmx.y);
      v.z = fminf(fmaxf(td - cpr.z, 0.0f), pmx.z);
      v.w = fminf(fmaxf(td - cpr.w, 0.0f), pmx.w);
      *(float4*)op = v;
      r += 8;
      op += 800;
    }
  }
}

__global__ __launch_bounds__(256, 1) void e2e_mlp_fused_kernel(
    const float* __restrict__ x,    const float* __restrict__ Cost,
    const float* __restrict__ Pmax, const float* __restrict__ Pd,
    const float* __restrict__ wcapp,const float* __restrict__ W1,
    const float* __restrict__ b1,   const float* __restrict__ W2,
    const float* __restrict__ b2,   const float* __restrict__ W3,
    const float* __restrict__ b3p,  float* __restrict__ out) {
  __shared__ float s[SMEM_FLOATS];
  const int t = threadIdx.x;
  const long rbase = (long)blockIdx.x * ROWS_PER_BLOCK;

  // ---- prep: stage weights (transposed+padded), Cost/Pmax, sum(Pd) ----
  for (int idx = t; idx < 960; idx += 256) {
    const int k = idx >> 5, i = idx & 31;
    float v;
    if (i < 30)       v = W2[i * 30 + k];
    else if (i == 30) v = b2[k];
    else              v = W3[k];
    s[OFF_W2 + idx] = v;
  }
  if (t < 240) {
    const int k = t >> 3, i = t & 7;
    float v = 0.0f;
    if (i < 4)       v = W1[i * 30 + k];
    else if (i == 4) v = b1[k];
    s[OFF_W1 + t] = v;
  }
  if (t < 100) {
    s[OFF_PM + t] = Pmax[t];
    s[OFF_CS + t] = Cost[t];
  }
  // sum(Pd): lanes 0..24 hold float4 partials, full-wave shfl reduce.
  {
    float p = 0.0f;
    if (t < 25) {
      const float4 q = ((const float4*)Pd)[t];
      p = q.x + q.y + q.z + q.w;
    }
    for (int off = 32; off; off >>= 1) p += __shfl_down(p, off, 64);
    if (t == 0) s[OFF_SPD] = p;
  }
  __syncthreads();  // B0

  // cumprev via O(N^2) rank-sum (stable tie-break == jnp stable argsort)
  if (t < 100) {
    const float c = s[OFF_CS + t];
    float acc = 0.0f;
    for (int i = 0; i < 100; ++i) {
      const float ci = s[OFF_CS + i];
      const bool cheaper = (ci < c) || (ci == c && i < t);
      acc += cheaper ? s[OFF_PM + i] : 0.0f;
    }
    s[OFF_CP + t] = acc;
  }

  const float wc  = wcapp[0];
  const float b3v = b3p[0];
  const float spd = s[OFF_SPD];
  const float4* __restrict__ x4 = (const float4*)x;

  // ---- chain 0: rows [0,512) of this block ----
  {
    const float4 xa = x4[rbase + t];
    const float4 xb = x4[rbase + 256 + t];
    const f2 td = mlp_pair(xa, xb, s, wc, b3v, spd);
    s[OFF_Y + t]       = td.x;
    s[OFF_Y + 256 + t] = td.y;
  }
  __syncthreads();  // B1 (covers cumprev + ybuf[0..511])

  float4 cpr = {0, 0, 0, 0}, pmx = {0, 0, 0, 0};
  if (t < 200) {
    const int g = t % 25;
    cpr = *(const float4*)&s[OFF_CP + g * 4];
    pmx = *(const float4*)&s[OFF_PM + g * 4];
  }

  // batch-0 stores issue here; chain-1 compute runs while they drain.
  store_batch(out + rbase * 100, &s[OFF_Y], cpr, pmx, t);

  // ---- chain 1: rows [512,1024) ----
  {
    const float4 xa = x4[rbase + 512 + t];
    const float4 xb = x4[rbase + 768 + t];
    const f2 td = mlp_pair(xa, xb, s, wc, b3v, spd);
    s[OFF_Y + 512 + t] = td.x;
    s[OFF_Y + 768 + t] = td.y;
  }
  __syncthreads();  // B2

  store_batch(out + (rbase + 512) * 100, &s[OFF_Y + 512], cpr, pmx, t);
}

extern "C" void kernel_launch(void* const* d_in, const int* in_sizes, int n_in,
                              void* d_out, int out_size, void* d_ws, size_t ws_size,
                              hipStream_t stream) {
  const float* x    = (const float*)d_in[0];
  const float* Cost = (const float*)d_in[1];
  const float* Pmax = (const float*)d_in[2];
  const float* Pd   = (const float*)d_in[3];
  const float* wcap = (const float*)d_in[4];
  const float* W1   = (const float*)d_in[5];
  const float* b1   = (const float*)d_in[6];
  const float* W2   = (const float*)d_in[7];
  const float* b2   = (const float*)d_in[8];
  const float* W3   = (const float*)d_in[9];
  const float* b3   = (const float*)d_in[10];
  float* out = (float*)d_out;

  e2e_mlp_fused_kernel<<<NBLOCKS, 256, 0, stream>>>(
      x, Cost, Pmax, Pd, wcap, W1, b1, W2, b2, W3, b3, out);
}